// Round 23
// baseline (38.346 us; speedup 1.0000x reference)
//
#include <hip/hip_runtime.h>
#include <math.h>

#define BB 4
#define LL 256
#define TT 256
#define DD 512

// e^{2x} = exp2(x * 2/ln2)
#define EXP2K 2.885390081777927f

using short8  = __attribute__((ext_vector_type(8))) short;
using f32x4   = __attribute__((ext_vector_type(4))) float;

__device__ __forceinline__ unsigned cvt2bf(float a, float b) {
  unsigned r;
  asm("v_cvt_pk_bf16_f32 %0, %1, %2" : "=v"(r) : "v"(a), "v"(b));
  return r;  // lo = bf16(a), hi = bf16(b)
}

// ---------------------------------------------------------------------------
// Kernel 1: combined projection GEMM via bf16 MFMA, fp32 accumulate, with
// register-prefetch staging (R22-proven, unchanged).
// Rows 0..1023:   E1  = exp(2*(x@W1^T+b1))   f32 row-major [B*L, D]
// Rows 1024..2047: E2c = exp(2*(mem@W2^T+b2)) f32 CHUNKED [d>>2][b*T+t][d&3]
// ---------------------------------------------------------------------------
__global__ __launch_bounds__(256) void proj_gemm(
    const float* __restrict__ x, const float* __restrict__ mem,
    const float* __restrict__ W1, const float* __restrict__ b1,
    const float* __restrict__ W2, const float* __restrict__ b2,
    float* __restrict__ E1, float* __restrict__ E2c)
{
  __shared__ __align__(16) char Abuf[32 * 144];   // 32 rows x 64 bf16 (+pad)
  __shared__ __align__(16) char Bbuf[64 * 144];   // 64 cols x 64 bf16 (+pad)

  const int tid = threadIdx.x;
  const int m0 = blockIdx.x * 32;      // 0..2047 in steps of 32
  const int n0 = blockIdx.y * 64;      // 0..511  in steps of 64
  const bool second = (m0 >= BB * LL);

  const float* A    = second ? mem + (size_t)(m0 - BB * LL) * DD
                             : x   + (size_t)m0 * DD;
  const float* W    = second ? W2 : W1;
  const float* bias = second ? b2 : b1;

  const int srow = tid >> 4;           // 0..15 staging row
  const int kq   = (tid & 15) * 4;     // k quad within 64

  const int lane = tid & 63;
  const int wid  = tid >> 6;
  const int r0   = (wid & 1) * 16;
  const int n0w  = (wid >> 1) * 32;
  const int lr   = lane & 15;
  const int lg   = lane >> 4;

  const int aoff  = (r0 + lr) * 144 + lg * 16;
  const int boff0 = (n0w + lr) * 144 + lg * 16;
  const int boff1 = (n0w + 16 + lr) * 144 + lg * 16;

  f32x4 acc0 = {0.f, 0.f, 0.f, 0.f};
  f32x4 acc1 = {0.f, 0.f, 0.f, 0.f};

  const float* Ap = A + (size_t)srow * DD + kq;
  const float* Wp = W + (size_t)(n0 + srow) * DD + kq;

  // preload tile kc=0 into registers
  float4 rA0 = *(const float4*)(Ap);
  float4 rA1 = *(const float4*)(Ap + (size_t)16 * DD);
  float4 rB0 = *(const float4*)(Wp);
  float4 rB1 = *(const float4*)(Wp + (size_t)16 * DD);
  float4 rB2 = *(const float4*)(Wp + (size_t)32 * DD);
  float4 rB3 = *(const float4*)(Wp + (size_t)48 * DD);

  for (int kc = 0; kc < DD; kc += 64) {
    __syncthreads();   // previous iteration's frag reads done
    {
      uint2 u0 = {cvt2bf(rA0.x, rA0.y), cvt2bf(rA0.z, rA0.w)};
      *(uint2*)(Abuf + srow * 144 + kq * 2) = u0;
      uint2 u1 = {cvt2bf(rA1.x, rA1.y), cvt2bf(rA1.z, rA1.w)};
      *(uint2*)(Abuf + (srow + 16) * 144 + kq * 2) = u1;
      uint2 v0 = {cvt2bf(rB0.x, rB0.y), cvt2bf(rB0.z, rB0.w)};
      *(uint2*)(Bbuf + srow * 144 + kq * 2) = v0;
      uint2 v1 = {cvt2bf(rB1.x, rB1.y), cvt2bf(rB1.z, rB1.w)};
      *(uint2*)(Bbuf + (srow + 16) * 144 + kq * 2) = v1;
      uint2 v2 = {cvt2bf(rB2.x, rB2.y), cvt2bf(rB2.z, rB2.w)};
      *(uint2*)(Bbuf + (srow + 32) * 144 + kq * 2) = v2;
      uint2 v3 = {cvt2bf(rB3.x, rB3.y), cvt2bf(rB3.z, rB3.w)};
      *(uint2*)(Bbuf + (srow + 48) * 144 + kq * 2) = v3;
    }
    __syncthreads();   // LDS tile ready
    if (kc + 64 < DD) {   // prefetch next tile; retires under MFMA
      const float* An = Ap + kc + 64;
      const float* Wn = Wp + kc + 64;
      rA0 = *(const float4*)(An);
      rA1 = *(const float4*)(An + (size_t)16 * DD);
      rB0 = *(const float4*)(Wn);
      rB1 = *(const float4*)(Wn + (size_t)16 * DD);
      rB2 = *(const float4*)(Wn + (size_t)32 * DD);
      rB3 = *(const float4*)(Wn + (size_t)48 * DD);
    }
#pragma unroll
    for (int ks = 0; ks < 2; ++ks) {
      short8 af  = *(const short8*)(Abuf + aoff  + ks * 64);
      short8 bf0 = *(const short8*)(Bbuf + boff0 + ks * 64);
      short8 bf1 = *(const short8*)(Bbuf + boff1 + ks * 64);
      acc0 = __builtin_amdgcn_mfma_f32_16x16x32_bf16(af, bf0, acc0, 0, 0, 0);
      acc1 = __builtin_amdgcn_mfma_f32_16x16x32_bf16(af, bf1, acc1, 0, 0, 0);
    }
  }

  // epilogue: C layout col=lane&15, row=(lane>>4)*4+i
#pragma unroll
  for (int nf = 0; nf < 2; ++nf) {
    const f32x4 a = nf ? acc1 : acc0;
    const int col = n0 + n0w + nf * 16 + lr;
    const float bv = bias[col];
#pragma unroll
    for (int i = 0; i < 4; ++i) {
      const int mrow = m0 + r0 + lg * 4 + i;
      const float val = exp2f((a[i] + bv) * EXP2K);
      if (!second) {
        E1[(size_t)mrow * DD + col] = val;
      } else {
        const int m2 = mrow - BB * LL;
        E2c[((size_t)(col >> 2) * (BB * TT) + m2) * 4 + (col & 3)] = val;
      }
    }
  }
}

// ---------------------------------------------------------------------------
// Kernel 2: score + softmax — 4-ROW QUAD SHARING. Block (b,lp) owns rows
// {lp, 127-lp, 128+lp, 255-lp}, whose causal tile needs are exactly
// tc >= {0,1,2,3}: tile tc is loaded ONCE and feeds tc+1 rows. E2c traffic
// 230 -> 128 MB; avg compute per 16B load 1.4 -> 2.5 row-units. 256 blocks
// x 1024 threads (16 waves x d-32nd, j=8) = 1 block/CU = 4 waves/SIMD
// (same occupancy as R22; VGPR headroom <=128 at this occupancy).
// Zero barriers in the tile loop; one 64KB LDS dump + one barrier + one
// 1024-thread cross-slot reduce (S fully initialized); softmax on waves
// 0-3; normalized f32 P store (proven handoff idiom).
// ---------------------------------------------------------------------------
#define SROW(r, q)                                                            \
  a##r##0 = fmaf(w.x, __builtin_amdgcn_rcpf(fmaf(q.x, vv.x, 1.0f)), a##r##0); \
  a##r##1 = fmaf(w.y, __builtin_amdgcn_rcpf(fmaf(q.y, vv.y, 1.0f)), a##r##1); \
  a##r##2 = fmaf(w.z, __builtin_amdgcn_rcpf(fmaf(q.z, vv.z, 1.0f)), a##r##2); \
  a##r##3 = fmaf(w.w, __builtin_amdgcn_rcpf(fmaf(q.w, vv.w, 1.0f)), a##r##3)

__global__ __launch_bounds__(1024) void score_softmax(
    const float* __restrict__ E1, const float* __restrict__ E2c,
    const float* __restrict__ wt, const int* __restrict__ mask,
    float* __restrict__ Pg)
{
  __shared__ float prt[4][4][16][64];      // (row, tile, d-32nd, t-lane) 64KB
  __shared__ float S[4][TT];               // raw scores per row            4KB

  const int tid = threadIdx.x;             // 0..1023
  const int tl  = tid & 63;
  const int wv  = tid >> 6;                // 0..15
  const int dq  = __builtin_amdgcn_readfirstlane(wv);  // wave-uniform 32nd

  // XCD-affinity decode (bid%8 = XCD round-robin); 256 blocks total
  const int bid = blockIdx.x;              // 0..255
  const int k   = bid & 7;
  const int b   = k >> 1;
  const int lp  = (bid >> 3) + ((k & 1) << 5);   // 0..63

  const int r0 = lp;          // tile need: tc >= 0
  const int r1 = 127 - lp;    // tc >= 1
  const int r2 = 128 + lp;    // tc >= 2
  const int r3 = 255 - lp;    // tc >= 3

  const size_t strE2 = (size_t)(BB * TT);  // float4 stride per d4 plane
  const float4* wp  = (const float4*)wt + dq * 8;
  const float4* q0p = (const float4*)(E1 + (size_t)(b * LL + r0) * DD) + dq * 8;
  const float4* q1p = (const float4*)(E1 + (size_t)(b * LL + r1) * DD) + dq * 8;
  const float4* q2p = (const float4*)(E1 + (size_t)(b * LL + r2) * DD) + dq * 8;
  const float4* q3p = (const float4*)(E1 + (size_t)(b * LL + r3) * DD) + dq * 8;

  // ---- score phase: 4 tiles, NO barriers inside; tile tc feeds tc+1 rows --
#pragma unroll
  for (int tc = 0; tc < 4; ++tc) {
    const int t = tc * 64 + tl;
    const float4* vp = (const float4*)E2c + (size_t)(dq * 8) * strE2 + (b * TT + t);

    float a00=0,a01=0,a02=0,a03=0;
    float a10=0,a11=0,a12=0,a13=0;
    float a20=0,a21=0,a22=0,a23=0;
    float a30=0,a31=0,a32=0,a33=0;
#pragma unroll
    for (int j = 0; j < 8; ++j) {
      const float4 vv = vp[(size_t)j * strE2];
      const float4 w  = wp[j];
      const float4 q0 = q0p[j];
      SROW(0, q0);
      if (tc >= 1) { const float4 q1 = q1p[j]; SROW(1, q1); }
      if (tc >= 2) { const float4 q2 = q2p[j]; SROW(2, q2); }
      if (tc >= 3) { const float4 q3 = q3p[j]; SROW(3, q3); }
    }
    prt[0][tc][dq][tl] = (a00 + a01) + (a02 + a03);
    if (tc >= 1) prt[1][tc][dq][tl] = (a10 + a11) + (a12 + a13);
    if (tc >= 2) prt[2][tc][dq][tl] = (a20 + a21) + (a22 + a23);
    if (tc >= 3) prt[3][tc][dq][tl] = (a30 + a31) + (a32 + a33);
  }
  __syncthreads();

  // ---- single cross-slot reduce: 1024 threads, 1 (row,t) each ----
  {
    const int rr = tid >> 8;           // 0..3 (row slot; needs tc >= rr)
    const int t  = tid & 255;
    if ((t >> 6) >= rr) {
      const float* pp = &prt[rr][t >> 6][0][t & 63];
      float s = 0.f;
#pragma unroll
      for (int oc = 0; oc < 16; ++oc) s += pp[oc * 64];
      S[rr][t] = s;
    } else {
      S[rr][t] = 5e29f;               // -2*S = -1e30 (masked sentinel)
    }
  }
  __syncthreads();

  // ---- softmax + normalized f32 P store: waves 0..3 -> rows r0..r3 ----
  if (wv < 4) {
    const int row = (wv & 2) ? ((wv & 1) ? r3 : r2) : ((wv & 1) ? r1 : r0);
    const int tb = tl * 4;
    float4 h = *(const float4*)(&S[wv][tb]);
    const int4 mk = *(const int4*)(mask + b * TT + tb);
    float v0 = (tb + 0 >= row && mk.x != 0) ? -2.0f * h.x : -1e30f;
    float v1 = (tb + 1 >= row && mk.y != 0) ? -2.0f * h.y : -1e30f;
    float v2 = (tb + 2 >= row && mk.z != 0) ? -2.0f * h.z : -1e30f;
    float v3 = (tb + 3 >= row && mk.w != 0) ? -2.0f * h.w : -1e30f;
    float mx = fmaxf(fmaxf(v0, v1), fmaxf(v2, v3));
#pragma unroll
    for (int o = 1; o < 64; o <<= 1) mx = fmaxf(mx, __shfl_xor(mx, o));
    float e0 = __expf(v0 - mx), e1 = __expf(v1 - mx),
          e2 = __expf(v2 - mx), e3 = __expf(v3 - mx);
    float sm = (e0 + e1) + (e2 + e3);
#pragma unroll
    for (int o = 1; o < 64; o <<= 1) sm += __shfl_xor(sm, o);
    const float rinv = 1.0f / sm;            // butterfly: all lanes have sum
    float4 pv = {e0 * rinv, e1 * rinv, e2 * rinv, e3 * rinv};
    *(float4*)(Pg + (size_t)(b * LL + row) * TT + tb) = pv;
  }
}

// ---------------------------------------------------------------------------
// Kernel 3: PV as bf16-MFMA GEMM with register-prefetch staging (R22-proven,
// unchanged). out[b] = P[b] (MxK) x mem[b] (KxN), 32x64 tile, BK=64,
// 256 threads. A = Pg (f32) cvt'd to bf16 at LDS-write. B = mem staged with
// in-LDS transpose. fp32 accumulate, direct f32 store.
// ---------------------------------------------------------------------------
__global__ __launch_bounds__(256) void pv_gemm(
    const float* __restrict__ Pg, const float* __restrict__ mem,
    float* __restrict__ out)
{
  __shared__ __align__(16) char Abuf[32 * 144];   // 32 rows x 64 bf16 (+pad)
  __shared__ __align__(16) char Bbuf[64 * 144];   // 64 n-cols x 64 k bf16 (+pad)

  const int tid = threadIdx.x;
  const int bid = blockIdx.x;          // 0..255
  const int b   = bid >> 6;
  const int rem = bid & 63;
  const int m0  = (rem >> 3) * 32;
  const int n0  = (rem & 7) * 64;

  const int arow = tid >> 3;           // 0..31
  const int k8   = (tid & 7) * 8;      // 0..56
  const int nq   = tid & 15;           // n quad 0..15
  const int kp0  = tid >> 4;           // k-pair 0..15 (and +16)

  const int lane = tid & 63;
  const int wid  = tid >> 6;
  const int r0   = (wid & 1) * 16;
  const int n0w  = (wid >> 1) * 32;
  const int lr   = lane & 15;
  const int lg   = lane >> 4;

  const int aoff  = (r0 + lr) * 144 + lg * 16;
  const int boff0 = (n0w + lr) * 144 + lg * 16;
  const int boff1 = (n0w + 16 + lr) * 144 + lg * 16;

  f32x4 acc0 = {0.f, 0.f, 0.f, 0.f};
  f32x4 acc1 = {0.f, 0.f, 0.f, 0.f};

  const float* Pb = Pg + (size_t)(b * LL) * TT;
  const float* Mb = mem + (size_t)(b * TT) * DD;
  const float* Pa = Pb + (size_t)(m0 + arow) * TT + k8;
  const float* Mq = Mb + n0 + nq * 4;

  // preload tile kc=0
  float4 pa1 = *(const float4*)(Pa);
  float4 pa2 = *(const float4*)(Pa + 4);
  float4 fa0 = *(const float4*)(Mq + (size_t)(kp0 * 2) * DD);
  float4 fb0 = *(const float4*)(Mq + (size_t)(kp0 * 2 + 1) * DD);
  float4 fa1 = *(const float4*)(Mq + (size_t)((kp0 + 16) * 2) * DD);
  float4 fb1 = *(const float4*)(Mq + (size_t)((kp0 + 16) * 2 + 1) * DD);

  for (int kc = 0; kc < TT; kc += 64) {
    __syncthreads();
    // A: P tile — cvt at write time
    {
      uint4 u = {cvt2bf(pa1.x, pa1.y), cvt2bf(pa1.z, pa1.w),
                 cvt2bf(pa2.x, pa2.y), cvt2bf(pa2.z, pa2.w)};
      *(uint4*)(Abuf + arow * 144 + k8 * 2) = u;
    }
    // B: mem tile transpose-write
    {
      *(unsigned*)(Bbuf + (nq * 4 + 0) * 144 + kp0 * 4) = cvt2bf(fa0.x, fb0.x);
      *(unsigned*)(Bbuf + (nq * 4 + 1) * 144 + kp0 * 4) = cvt2bf(fa0.y, fb0.y);
      *(unsigned*)(Bbuf + (nq * 4 + 2) * 144 + kp0 * 4) = cvt2bf(fa0.z, fb0.z);
      *(unsigned*)(Bbuf + (nq * 4 + 3) * 144 + kp0 * 4) = cvt2bf(fa0.w, fb0.w);
      const int kp1 = kp0 + 16;
      *(unsigned*)(Bbuf + (nq * 4 + 0) * 144 + kp1 * 4) = cvt2bf(fa1.x, fb1.x);
      *(unsigned*)(Bbuf + (nq * 4 + 1) * 144 + kp1 * 4) = cvt2bf(fa1.y, fb1.y);
      *(unsigned*)(Bbuf + (nq * 4 + 2) * 144 + kp1 * 4) = cvt2bf(fa1.z, fb1.z);
      *(unsigned*)(Bbuf + (nq * 4 + 3) * 144 + kp1 * 4) = cvt2bf(fa1.w, fb1.w);
    }
    __syncthreads();
    if (kc + 64 < TT) {   // prefetch next tile; retires under MFMA
      const int kn = kc + 64;
      pa1 = *(const float4*)(Pa + kn);
      pa2 = *(const float4*)(Pa + kn + 4);
      fa0 = *(const float4*)(Mq + (size_t)(kn + kp0 * 2) * DD);
      fb0 = *(const float4*)(Mq + (size_t)(kn + kp0 * 2 + 1) * DD);
      fa1 = *(const float4*)(Mq + (size_t)(kn + (kp0 + 16) * 2) * DD);
      fb1 = *(const float4*)(Mq + (size_t)(kn + (kp0 + 16) * 2 + 1) * DD);
    }
#pragma unroll
    for (int ks = 0; ks < 2; ++ks) {
      short8 af  = *(const short8*)(Abuf + aoff  + ks * 64);
      short8 bf0 = *(const short8*)(Bbuf + boff0 + ks * 64);
      short8 bf1 = *(const short8*)(Bbuf + boff1 + ks * 64);
      acc0 = __builtin_amdgcn_mfma_f32_16x16x32_bf16(af, bf0, acc0, 0, 0, 0);
      acc1 = __builtin_amdgcn_mfma_f32_16x16x32_bf16(af, bf1, acc1, 0, 0, 0);
    }
  }

  // epilogue: direct f32 store (no bias/activation)
#pragma unroll
  for (int nf = 0; nf < 2; ++nf) {
    const f32x4 a = nf ? acc1 : acc0;
    const int col = n0 + n0w + nf * 16 + lr;
#pragma unroll
    for (int i = 0; i < 4; ++i) {
      const int mrow = m0 + r0 + lg * 4 + i;
      out[(size_t)(b * LL + mrow) * DD + col] = a[i];
    }
  }
}

extern "C" void kernel_launch(void* const* d_in, const int* in_sizes, int n_in,
                              void* d_out, int out_size, void* d_ws, size_t ws_size,
                              hipStream_t stream) {
  const float* x   = (const float*)d_in[0];
  const float* mem = (const float*)d_in[1];
  const float* W1  = (const float*)d_in[2];
  const float* b1  = (const float*)d_in[3];
  const float* W2  = (const float*)d_in[4];
  const float* b2  = (const float*)d_in[5];
  const float* wt  = (const float*)d_in[6];
  const int* mask  = (const int*)d_in[8];
  float* outp = (float*)d_out;

  float* E1  = (float*)d_ws;                     // [B*L, D]      2 MB f32
  float* E2c = E1 + (size_t)BB * LL * DD;        // chunked       2 MB f32
  float* Pg  = E2c + (size_t)BB * TT * DD;       // [B][L][T]     1 MB f32 (5 MB)

  proj_gemm<<<dim3((BB * LL + BB * TT) / 32, DD / 64), 256, 0, stream>>>(
      x, mem, W1, b1, W2, b2, E1, E2c);
  score_softmax<<<256, 1024, 0, stream>>>(E1, E2c, wt, mask, Pg);
  pv_gemm<<<256, 256, 0, stream>>>(Pg, mem, outp);
}

// Round 24
// 32.690 us; speedup vs baseline: 1.1730x; 1.1730x over previous
//
#include <hip/hip_runtime.h>
#include <math.h>

#define BB 4
#define LL 256
#define TT 256
#define DD 512

// e^{2x} = exp2(x * 2/ln2)
#define EXP2K 2.885390081777927f

using short8  = __attribute__((ext_vector_type(8))) short;
using f32x4   = __attribute__((ext_vector_type(4))) float;

__device__ __forceinline__ unsigned cvt2bf(float a, float b) {
  unsigned r;
  asm("v_cvt_pk_bf16_f32 %0, %1, %2" : "=v"(r) : "v"(a), "v"(b));
  return r;  // lo = bf16(a), hi = bf16(b)
}

// ---------------------------------------------------------------------------
// Kernel 1: combined projection GEMM via bf16 MFMA, fp32 accumulate, with
// register-prefetch staging (R22-proven, unchanged).
// Rows 0..1023:   E1  = exp(2*(x@W1^T+b1))   f32 row-major [B*L, D]
// Rows 1024..2047: E2c = exp(2*(mem@W2^T+b2)) f32 CHUNKED [d>>2][b*T+t][d&3]
// ---------------------------------------------------------------------------
__global__ __launch_bounds__(256) void proj_gemm(
    const float* __restrict__ x, const float* __restrict__ mem,
    const float* __restrict__ W1, const float* __restrict__ b1,
    const float* __restrict__ W2, const float* __restrict__ b2,
    float* __restrict__ E1, float* __restrict__ E2c)
{
  __shared__ __align__(16) char Abuf[32 * 144];   // 32 rows x 64 bf16 (+pad)
  __shared__ __align__(16) char Bbuf[64 * 144];   // 64 cols x 64 bf16 (+pad)

  const int tid = threadIdx.x;
  const int m0 = blockIdx.x * 32;      // 0..2047 in steps of 32
  const int n0 = blockIdx.y * 64;      // 0..511  in steps of 64
  const bool second = (m0 >= BB * LL);

  const float* A    = second ? mem + (size_t)(m0 - BB * LL) * DD
                             : x   + (size_t)m0 * DD;
  const float* W    = second ? W2 : W1;
  const float* bias = second ? b2 : b1;

  const int srow = tid >> 4;           // 0..15 staging row
  const int kq   = (tid & 15) * 4;     // k quad within 64

  const int lane = tid & 63;
  const int wid  = tid >> 6;
  const int r0   = (wid & 1) * 16;
  const int n0w  = (wid >> 1) * 32;
  const int lr   = lane & 15;
  const int lg   = lane >> 4;

  const int aoff  = (r0 + lr) * 144 + lg * 16;
  const int boff0 = (n0w + lr) * 144 + lg * 16;
  const int boff1 = (n0w + 16 + lr) * 144 + lg * 16;

  f32x4 acc0 = {0.f, 0.f, 0.f, 0.f};
  f32x4 acc1 = {0.f, 0.f, 0.f, 0.f};

  const float* Ap = A + (size_t)srow * DD + kq;
  const float* Wp = W + (size_t)(n0 + srow) * DD + kq;

  // preload tile kc=0 into registers
  float4 rA0 = *(const float4*)(Ap);
  float4 rA1 = *(const float4*)(Ap + (size_t)16 * DD);
  float4 rB0 = *(const float4*)(Wp);
  float4 rB1 = *(const float4*)(Wp + (size_t)16 * DD);
  float4 rB2 = *(const float4*)(Wp + (size_t)32 * DD);
  float4 rB3 = *(const float4*)(Wp + (size_t)48 * DD);

  for (int kc = 0; kc < DD; kc += 64) {
    __syncthreads();   // previous iteration's frag reads done
    {
      uint2 u0 = {cvt2bf(rA0.x, rA0.y), cvt2bf(rA0.z, rA0.w)};
      *(uint2*)(Abuf + srow * 144 + kq * 2) = u0;
      uint2 u1 = {cvt2bf(rA1.x, rA1.y), cvt2bf(rA1.z, rA1.w)};
      *(uint2*)(Abuf + (srow + 16) * 144 + kq * 2) = u1;
      uint2 v0 = {cvt2bf(rB0.x, rB0.y), cvt2bf(rB0.z, rB0.w)};
      *(uint2*)(Bbuf + srow * 144 + kq * 2) = v0;
      uint2 v1 = {cvt2bf(rB1.x, rB1.y), cvt2bf(rB1.z, rB1.w)};
      *(uint2*)(Bbuf + (srow + 16) * 144 + kq * 2) = v1;
      uint2 v2 = {cvt2bf(rB2.x, rB2.y), cvt2bf(rB2.z, rB2.w)};
      *(uint2*)(Bbuf + (srow + 32) * 144 + kq * 2) = v2;
      uint2 v3 = {cvt2bf(rB3.x, rB3.y), cvt2bf(rB3.z, rB3.w)};
      *(uint2*)(Bbuf + (srow + 48) * 144 + kq * 2) = v3;
    }
    __syncthreads();   // LDS tile ready
    if (kc + 64 < DD) {   // prefetch next tile; retires under MFMA
      const float* An = Ap + kc + 64;
      const float* Wn = Wp + kc + 64;
      rA0 = *(const float4*)(An);
      rA1 = *(const float4*)(An + (size_t)16 * DD);
      rB0 = *(const float4*)(Wn);
      rB1 = *(const float4*)(Wn + (size_t)16 * DD);
      rB2 = *(const float4*)(Wn + (size_t)32 * DD);
      rB3 = *(const float4*)(Wn + (size_t)48 * DD);
    }
#pragma unroll
    for (int ks = 0; ks < 2; ++ks) {
      short8 af  = *(const short8*)(Abuf + aoff  + ks * 64);
      short8 bf0 = *(const short8*)(Bbuf + boff0 + ks * 64);
      short8 bf1 = *(const short8*)(Bbuf + boff1 + ks * 64);
      acc0 = __builtin_amdgcn_mfma_f32_16x16x32_bf16(af, bf0, acc0, 0, 0, 0);
      acc1 = __builtin_amdgcn_mfma_f32_16x16x32_bf16(af, bf1, acc1, 0, 0, 0);
    }
  }

  // epilogue: C layout col=lane&15, row=(lane>>4)*4+i
#pragma unroll
  for (int nf = 0; nf < 2; ++nf) {
    const f32x4 a = nf ? acc1 : acc0;
    const int col = n0 + n0w + nf * 16 + lr;
    const float bv = bias[col];
#pragma unroll
    for (int i = 0; i < 4; ++i) {
      const int mrow = m0 + r0 + lg * 4 + i;
      const float val = exp2f((a[i] + bv) * EXP2K);
      if (!second) {
        E1[(size_t)mrow * DD + col] = val;
      } else {
        const int m2 = mrow - BB * LL;
        E2c[((size_t)(col >> 2) * (BB * TT) + m2) * 4 + (col & 3)] = val;
      }
    }
  }
}

// ---------------------------------------------------------------------------
// Kernel 2: score + softmax (R20/R22-proven). 512 threads, 8 waves x
// d-octant; zero barriers in the tile loop; one combined cross-octant
// reduce; S fully initialized; normalized f32 P store. Anti-diagonal tile
// sharing (tc >= tc1: one vv load feeds both rows). XCD-affinity decode.
// ---------------------------------------------------------------------------
__global__ __launch_bounds__(512) void score_softmax(
    const float* __restrict__ E1, const float* __restrict__ E2c,
    const float* __restrict__ wt, const int* __restrict__ mask,
    float* __restrict__ Pg)
{
  __shared__ float prt[2][4][8][64];       // (row, tile, d-octant, t-lane) 16KB
  __shared__ float S[2][TT];               // raw scores per row             2KB

  const int tid = threadIdx.x;             // 0..511
  const int tl  = tid & 63;
  const int wv  = tid >> 6;                // 0..7
  const int dq  = __builtin_amdgcn_readfirstlane(wv);  // wave-uniform octant

  // XCD-affinity decode (bid%8 = XCD round-robin)
  const int bid = blockIdx.x;              // 0..511
  const int k   = bid & 7;
  const int b   = k >> 1;
  const int lp  = (bid >> 3) + ((k & 1) << 6);   // 0..127

  const int r0 = lp;
  const int r1 = 255 - lp;
  const int tc0 = r0 >> 6;          // 0 or 1
  const int tc1 = r1 >> 6;          // 3 or 2  (tc1 == 3 - tc0)

  const size_t strE2 = (size_t)(BB * TT);  // float4 stride per d4 plane
  const float4* wp  = (const float4*)wt + dq * 16;
  const float4* q0p = (const float4*)(E1 + (size_t)(b * LL + r0) * DD) + dq * 16;
  const float4* q1p = (const float4*)(E1 + (size_t)(b * LL + r1) * DD) + dq * 16;

  // ---- score phase: loop over tiles, NO barriers inside ----
  for (int tc = tc0; tc < 4; ++tc) {
    const bool shr = (tc >= tc1);          // block-uniform
    const int t = tc * 64 + tl;
    const float4* vp = (const float4*)E2c + (size_t)(dq * 16) * strE2 + (b * TT + t);

    float a0 = 0.f, a1 = 0.f, a2 = 0.f, a3 = 0.f;
    float b0 = 0.f, b1 = 0.f, b2 = 0.f, b3 = 0.f;
    if (shr) {
#pragma unroll 8
      for (int j = 0; j < 16; ++j) {
        float4 vv = vp[(size_t)j * strE2];
        float4 q0 = q0p[j];
        float4 q1 = q1p[j];
        float4 w  = wp[j];
        a0 = fmaf(w.x, __builtin_amdgcn_rcpf(fmaf(q0.x, vv.x, 1.0f)), a0);
        a1 = fmaf(w.y, __builtin_amdgcn_rcpf(fmaf(q0.y, vv.y, 1.0f)), a1);
        a2 = fmaf(w.z, __builtin_amdgcn_rcpf(fmaf(q0.z, vv.z, 1.0f)), a2);
        a3 = fmaf(w.w, __builtin_amdgcn_rcpf(fmaf(q0.w, vv.w, 1.0f)), a3);
        b0 = fmaf(w.x, __builtin_amdgcn_rcpf(fmaf(q1.x, vv.x, 1.0f)), b0);
        b1 = fmaf(w.y, __builtin_amdgcn_rcpf(fmaf(q1.y, vv.y, 1.0f)), b1);
        b2 = fmaf(w.z, __builtin_amdgcn_rcpf(fmaf(q1.z, vv.z, 1.0f)), b2);
        b3 = fmaf(w.w, __builtin_amdgcn_rcpf(fmaf(q1.w, vv.w, 1.0f)), b3);
      }
    } else {
#pragma unroll 8
      for (int j = 0; j < 16; ++j) {
        float4 vv = vp[(size_t)j * strE2];
        float4 q0 = q0p[j];
        float4 w  = wp[j];
        a0 = fmaf(w.x, __builtin_amdgcn_rcpf(fmaf(q0.x, vv.x, 1.0f)), a0);
        a1 = fmaf(w.y, __builtin_amdgcn_rcpf(fmaf(q0.y, vv.y, 1.0f)), a1);
        a2 = fmaf(w.z, __builtin_amdgcn_rcpf(fmaf(q0.z, vv.z, 1.0f)), a2);
        a3 = fmaf(w.w, __builtin_amdgcn_rcpf(fmaf(q0.w, vv.w, 1.0f)), a3);
      }
    }
    prt[0][tc][dq][tl] = (a0 + a1) + (a2 + a3);
    if (shr) prt[1][tc][dq][tl] = (b0 + b1) + (b2 + b3);
  }
  __syncthreads();

  // ---- single cross-octant reduce: 512 threads; S fully initialized ----
  {
    const int rr = tid >> 8;           // 0..1
    const int t  = tid & 255;
    const int lo = (rr ? tc1 : tc0) << 6;
    if (t >= lo) {
      const float* pp = &prt[rr][t >> 6][0][t & 63];
      float s = 0.f;
#pragma unroll
      for (int oc = 0; oc < 8; ++oc) s += pp[oc * 64];
      S[rr][t] = s;
    } else {
      S[rr][t] = 5e29f;               // -2*S = -1e30 (masked sentinel)
    }
  }
  __syncthreads();

  // ---- softmax + normalized f32 P store: wave 0 -> r0, wave 1 -> r1 ----
  if (wv < 2) {
    const int row = wv ? r1 : r0;
    const int tb = tl * 4;
    float4 h = *(const float4*)(&S[wv][tb]);
    const int4 mk = *(const int4*)(mask + b * TT + tb);
    float v0 = (tb + 0 >= row && mk.x != 0) ? -2.0f * h.x : -1e30f;
    float v1 = (tb + 1 >= row && mk.y != 0) ? -2.0f * h.y : -1e30f;
    float v2 = (tb + 2 >= row && mk.z != 0) ? -2.0f * h.z : -1e30f;
    float v3 = (tb + 3 >= row && mk.w != 0) ? -2.0f * h.w : -1e30f;
    float mx = fmaxf(fmaxf(v0, v1), fmaxf(v2, v3));
#pragma unroll
    for (int o = 1; o < 64; o <<= 1) mx = fmaxf(mx, __shfl_xor(mx, o));
    float e0 = __expf(v0 - mx), e1 = __expf(v1 - mx),
          e2 = __expf(v2 - mx), e3 = __expf(v3 - mx);
    float sm = (e0 + e1) + (e2 + e3);
#pragma unroll
    for (int o = 1; o < 64; o <<= 1) sm += __shfl_xor(sm, o);
    const float rinv = 1.0f / sm;            // butterfly: all lanes have sum
    float4 pv = {e0 * rinv, e1 * rinv, e2 * rinv, e3 * rinv};
    *(float4*)(Pg + (size_t)(b * LL + row) * TT + tb) = pv;
  }
}

// ---------------------------------------------------------------------------
// Kernel 3: PV as bf16-MFMA GEMM with register-prefetch staging (R22-proven,
// unchanged). out[b] = P[b] (MxK) x mem[b] (KxN), 32x64 tile, BK=64,
// 256 threads. A = Pg (f32) cvt'd to bf16 at LDS-write. B = mem staged with
// in-LDS transpose. fp32 accumulate, direct f32 store.
// ---------------------------------------------------------------------------
__global__ __launch_bounds__(256) void pv_gemm(
    const float* __restrict__ Pg, const float* __restrict__ mem,
    float* __restrict__ out)
{
  __shared__ __align__(16) char Abuf[32 * 144];   // 32 rows x 64 bf16 (+pad)
  __shared__ __align__(16) char Bbuf[64 * 144];   // 64 n-cols x 64 k bf16 (+pad)

  const int tid = threadIdx.x;
  const int bid = blockIdx.x;          // 0..255
  const int b   = bid >> 6;
  const int rem = bid & 63;
  const int m0  = (rem >> 3) * 32;
  const int n0  = (rem & 7) * 64;

  const int arow = tid >> 3;           // 0..31
  const int k8   = (tid & 7) * 8;      // 0..56
  const int nq   = tid & 15;           // n quad 0..15
  const int kp0  = tid >> 4;           // k-pair 0..15 (and +16)

  const int lane = tid & 63;
  const int wid  = tid >> 6;
  const int r0   = (wid & 1) * 16;
  const int n0w  = (wid >> 1) * 32;
  const int lr   = lane & 15;
  const int lg   = lane >> 4;

  const int aoff  = (r0 + lr) * 144 + lg * 16;
  const int boff0 = (n0w + lr) * 144 + lg * 16;
  const int boff1 = (n0w + 16 + lr) * 144 + lg * 16;

  f32x4 acc0 = {0.f, 0.f, 0.f, 0.f};
  f32x4 acc1 = {0.f, 0.f, 0.f, 0.f};

  const float* Pb = Pg + (size_t)(b * LL) * TT;
  const float* Mb = mem + (size_t)(b * TT) * DD;
  const float* Pa = Pb + (size_t)(m0 + arow) * TT + k8;
  const float* Mq = Mb + n0 + nq * 4;

  // preload tile kc=0
  float4 pa1 = *(const float4*)(Pa);
  float4 pa2 = *(const float4*)(Pa + 4);
  float4 fa0 = *(const float4*)(Mq + (size_t)(kp0 * 2) * DD);
  float4 fb0 = *(const float4*)(Mq + (size_t)(kp0 * 2 + 1) * DD);
  float4 fa1 = *(const float4*)(Mq + (size_t)((kp0 + 16) * 2) * DD);
  float4 fb1 = *(const float4*)(Mq + (size_t)((kp0 + 16) * 2 + 1) * DD);

  for (int kc = 0; kc < TT; kc += 64) {
    __syncthreads();
    // A: P tile — cvt at write time
    {
      uint4 u = {cvt2bf(pa1.x, pa1.y), cvt2bf(pa1.z, pa1.w),
                 cvt2bf(pa2.x, pa2.y), cvt2bf(pa2.z, pa2.w)};
      *(uint4*)(Abuf + arow * 144 + k8 * 2) = u;
    }
    // B: mem tile transpose-write
    {
      *(unsigned*)(Bbuf + (nq * 4 + 0) * 144 + kp0 * 4) = cvt2bf(fa0.x, fb0.x);
      *(unsigned*)(Bbuf + (nq * 4 + 1) * 144 + kp0 * 4) = cvt2bf(fa0.y, fb0.y);
      *(unsigned*)(Bbuf + (nq * 4 + 2) * 144 + kp0 * 4) = cvt2bf(fa0.z, fb0.z);
      *(unsigned*)(Bbuf + (nq * 4 + 3) * 144 + kp0 * 4) = cvt2bf(fa0.w, fb0.w);
      const int kp1 = kp0 + 16;
      *(unsigned*)(Bbuf + (nq * 4 + 0) * 144 + kp1 * 4) = cvt2bf(fa1.x, fb1.x);
      *(unsigned*)(Bbuf + (nq * 4 + 1) * 144 + kp1 * 4) = cvt2bf(fa1.y, fb1.y);
      *(unsigned*)(Bbuf + (nq * 4 + 2) * 144 + kp1 * 4) = cvt2bf(fa1.z, fb1.z);
      *(unsigned*)(Bbuf + (nq * 4 + 3) * 144 + kp1 * 4) = cvt2bf(fa1.w, fb1.w);
    }
    __syncthreads();
    if (kc + 64 < TT) {   // prefetch next tile; retires under MFMA
      const int kn = kc + 64;
      pa1 = *(const float4*)(Pa + kn);
      pa2 = *(const float4*)(Pa + kn + 4);
      fa0 = *(const float4*)(Mq + (size_t)(kn + kp0 * 2) * DD);
      fb0 = *(const float4*)(Mq + (size_t)(kn + kp0 * 2 + 1) * DD);
      fa1 = *(const float4*)(Mq + (size_t)(kn + (kp0 + 16) * 2) * DD);
      fb1 = *(const float4*)(Mq + (size_t)(kn + (kp0 + 16) * 2 + 1) * DD);
    }
#pragma unroll
    for (int ks = 0; ks < 2; ++ks) {
      short8 af  = *(const short8*)(Abuf + aoff  + ks * 64);
      short8 bf0 = *(const short8*)(Bbuf + boff0 + ks * 64);
      short8 bf1 = *(const short8*)(Bbuf + boff1 + ks * 64);
      acc0 = __builtin_amdgcn_mfma_f32_16x16x32_bf16(af, bf0, acc0, 0, 0, 0);
      acc1 = __builtin_amdgcn_mfma_f32_16x16x32_bf16(af, bf1, acc1, 0, 0, 0);
    }
  }

  // epilogue: direct f32 store (no bias/activation)
#pragma unroll
  for (int nf = 0; nf < 2; ++nf) {
    const f32x4 a = nf ? acc1 : acc0;
    const int col = n0 + n0w + nf * 16 + lr;
#pragma unroll
    for (int i = 0; i < 4; ++i) {
      const int mrow = m0 + r0 + lg * 4 + i;
      out[(size_t)(b * LL + mrow) * DD + col] = a[i];
    }
  }
}

extern "C" void kernel_launch(void* const* d_in, const int* in_sizes, int n_in,
                              void* d_out, int out_size, void* d_ws, size_t ws_size,
                              hipStream_t stream) {
  const float* x   = (const float*)d_in[0];
  const float* mem = (const float*)d_in[1];
  const float* W1  = (const float*)d_in[2];
  const float* b1  = (const float*)d_in[3];
  const float* W2  = (const float*)d_in[4];
  const float* b2  = (const float*)d_in[5];
  const float* wt  = (const float*)d_in[6];
  const int* mask  = (const int*)d_in[8];
  float* outp = (float*)d_out;

  float* E1  = (float*)d_ws;                     // [B*L, D]      2 MB f32
  float* E2c = E1 + (size_t)BB * LL * DD;        // chunked       2 MB f32
  float* Pg  = E2c + (size_t)BB * TT * DD;       // [B][L][T]     1 MB f32 (5 MB)

  proj_gemm<<<dim3((BB * LL + BB * TT) / 32, DD / 64), 256, 0, stream>>>(
      x, mem, W1, b1, W2, b2, E1, E2c);
  score_softmax<<<512, 512, 0, stream>>>(E1, E2c, wt, mask, Pg);
  pv_gemm<<<256, 256, 0, stream>>>(Pg, mem, outp);
}